// Round 8
// baseline (3541.285 us; speedup 1.0000x reference)
//
#include <hip/hip_runtime.h>
#include <hip/hip_bf16.h>
#include <stdint.h>

// GRU-D encoder, MI355X persistent-kernel implementation, round 8.
// B=256, S=200, D=64, H=512, TD=8.
// 8 clusters, each serving TWO 16-row chains (rb pair) with one WG-set:
// 4 gate WGs (r+h K=640 fused, 80 resident B-frags shared across both rbs),
// 4 z WGs, 1 gamma WG. Interleaved schedule rb0.hop1 -> rb1.hop1 ->
// rb0.hop2 -> rb1.hop2 hides each chain's flag/data round-trip latency
// under the other chain's compute. 72 WGs total. Fuel-bounded polls.

typedef unsigned short u16;
typedef unsigned int   u32;
typedef unsigned long long u64;
typedef short bfrag  __attribute__((ext_vector_type(8)));
typedef u16   u16x8  __attribute__((ext_vector_type(8)));
typedef float f32x4  __attribute__((ext_vector_type(4)));

#define NB 256
#define NS 200
#define ND 64
#define NH 512

#define MFMA(a,b,c) __builtin_amdgcn_mfma_f32_16x16x32_bf16((a),(b),(c),0,0,0)

union UQ { u16x8 h; bfrag s; u64 u[2]; uint4 q; };

__device__ __forceinline__ float b2f(u16 v){ union { float f; u32 u; } c; c.u = ((u32)v) << 16; return c.f; }
__device__ __forceinline__ u16 f2b(float f){ union { float f; u32 u; } c; c.f = f; u32 r = c.u + 0x7FFFu + ((c.u >> 16) & 1u); return (u16)(r >> 16); }
__device__ __forceinline__ float sigm(float x){ return 1.f / (1.f + __expf(-x)); }
__device__ __forceinline__ float tanh_f(float x){ return 1.f - 2.f / (1.f + __expf(2.f * x)); }

__device__ __forceinline__ u64 cload64(const void* p){
  return __hip_atomic_load((const u64*)p, __ATOMIC_RELAXED, __HIP_MEMORY_SCOPE_AGENT);
}
__device__ __forceinline__ void cstore64(void* p, u64 v){
  __hip_atomic_store((u64*)p, v, __ATOMIC_RELAXED, __HIP_MEMORY_SCOPE_AGENT);
}
__device__ __forceinline__ u32 cload32(const u32* p){
  return __hip_atomic_load(p, __ATOMIC_RELAXED, __HIP_MEMORY_SCOPE_AGENT);
}
__device__ __forceinline__ void cstore32(u32* p, u32 v){
  __hip_atomic_store(p, v, __ATOMIC_RELAXED, __HIP_MEMORY_SCOPE_AGENT);
}
// lane-parallel poll, fuel-bounded (fail fast, no GPU hang)
__device__ __forceinline__ bool poll_ge(const u32* wp, u32 tgt){
  int fuel = 1 << 20;
  while (true) {
    u32 v = cload32(wp);
    if (__all(v >= tgt)) return true;
    if (--fuel == 0) return false;
  }
}
__device__ __forceinline__ bfrag ldfrag(const float* src){
  f32x4 lo = *(const f32x4*)src;
  f32x4 hi = *(const f32x4*)(src + 4);
  UQ z;
  z.h[0]=f2b(lo[0]); z.h[1]=f2b(lo[1]); z.h[2]=f2b(lo[2]); z.h[3]=f2b(lo[3]);
  z.h[4]=f2b(hi[0]); z.h[5]=f2b(hi[1]); z.h[6]=f2b(hi[2]); z.h[7]=f2b(hi[3]);
  return z.s;
}
// B-frag source for the K=640 concat [U | W | V]
__device__ __forceinline__ const float* wsrc(const float* Um, const float* Wm,
                                             const float* Vm, int c, int k0){
  if (k0 < 512) return Um + (size_t)c * 512 + k0;
  if (k0 < 576) return Wm + (size_t)c * 64 + (k0 - 512);
  return Vm + (size_t)c * 64 + (k0 - 576);
}
// cooperative coalesced staging of a [16][512] bf16 block into an A-panel
__device__ __forceinline__ void stage_bf16(u16* dst, const u16* src, int tid, bool zero){
  const int row = tid >> 4, sc = (tid & 15) * 32;
  u16* dp = &dst[((sc >> 3) * 16 + row) * 8];
  if (!zero) {
    const u16* hs = src + (size_t)row * 512 + sc;
    u64 a0 = cload64(hs),      a1 = cload64(hs + 4),  a2 = cload64(hs + 8),  a3 = cload64(hs + 12);
    u64 a4 = cload64(hs + 16), a5 = cload64(hs + 20), a6 = cload64(hs + 24), a7 = cload64(hs + 28);
    *(u64*)(dp)       = a0; *(u64*)(dp + 4)   = a1;
    *(u64*)(dp + 128) = a2; *(u64*)(dp + 132) = a3;
    *(u64*)(dp + 256) = a4; *(u64*)(dp + 260) = a5;
    *(u64*)(dp + 384) = a6; *(u64*)(dp + 388) = a7;
  } else {
    *(u64*)(dp)       = 0; *(u64*)(dp + 4)   = 0;
    *(u64*)(dp + 128) = 0; *(u64*)(dp + 132) = 0;
    *(u64*)(dp + 256) = 0; *(u64*)(dp + 260) = 0;
    *(u64*)(dp + 384) = 0; *(u64*)(dp + 388) = 0;
  }
}

// ---------------- setup kernels ----------------

__global__ void transpose_k(const float* __restrict__ Wout, float* __restrict__ WT){
  int i = blockIdx.x * 256 + threadIdx.x;
  if (i < 520 * 512) { int k = i >> 9, ho = i & 511; WT[i] = Wout[ho * 520 + k]; }
}

__global__ void mean1_k(const float* __restrict__ x, const float* __restrict__ mask,
                        float* __restrict__ PX, float* __restrict__ PM){
  int s = blockIdx.x, tid = threadIdx.x;
  __shared__ float lx[256], lm[256];
  float xa = 0.f, ma = 0.f;
  for (int i = tid; i < NB * ND; i += 256) {
    int b = i >> 6, d = i & 63;
    size_t ix = ((size_t)b * NS + s) * 64 + d;
    float m = mask[ix];
    xa += m * x[ix]; ma += m;
  }
  lx[tid] = xa; lm[tid] = ma;
  __syncthreads();
  if (tid < 64) {
    PX[(size_t)s * 64 + tid] = lx[tid] + lx[tid + 64] + lx[tid + 128] + lx[tid + 192];
    PM[(size_t)s * 64 + tid] = lm[tid] + lm[tid + 64] + lm[tid + 128] + lm[tid + 192];
  }
}

__global__ void mean2_k(const float* __restrict__ PX, const float* __restrict__ PM,
                        float* __restrict__ XMEAN){
  int d = threadIdx.x;
  float sx = 0.f, sm = 0.f;
  for (int s = 0; s < NS; ++s){ sx += PX[s * 64 + d]; sm += PM[s * 64 + d]; }
  XMEAN[d] = sx / fmaxf(sm, 1.f);
}

__global__ void prep_k(const float* __restrict__ x, const float* __restrict__ mask,
                       const float* __restrict__ tc, const float* __restrict__ wdgx,
                       const float* __restrict__ bdgx, const float* __restrict__ XMEAN,
                       u16* __restrict__ XHAT, u16* __restrict__ MASKB, u16* __restrict__ DELTA){
  int g = blockIdx.x * 256 + threadIdx.x;
  int b = g >> 6, d = g & 63;
  float xmean = XMEAN[d], wx = wdgx[d], bx = bdgx[d];
  float xl = 0.f, del = 0.f, tprev = 0.f, mprev = 1.f;
  for (int s = 0; s < NS; ++s){
    float tv = tc[b * NS + s];
    float dtv = (s == 0) ? 0.f : (tv - tprev);
    tprev = tv;
    del = dtv + (1.f - mprev) * del;
    size_t ix = ((size_t)b * NS + s) * 64 + d;
    float m = mask[ix], xv = x[ix];
    float gx = __expf(-fmaxf(0.f, wx * del + bx));
    float xh = m * xv + (1.f - m) * (gx * xl + (1.f - gx) * xmean);
    size_t ox = ((size_t)s * NB + b) * 64 + d;
    XHAT[ox] = f2b(xh); MASKB[ox] = f2b(m); DELTA[ox] = f2b(del);
    xl = m * xv + (1.f - m) * xl;
    mprev = m;
  }
}

// ---------------- persistent recurrent kernel ----------------
// grid = 72 WGs (8 clusters x 9), 256 threads (4 waves).
// cluster serves rb pair (2c, 2c+1).
// role 0..3 : gate WG — 32 cols/wave of r AND h-candidate (K=640 fused)
// role 4..7 : z WG    — 32 cols/wave of z (K=640 fused)
// role 8    : gamma producer (double-buffered, paced)
// Flags per rb (stride 64 u32): FH[16]@0, FR[16]@16, FZ[16]@32, FG@48.
__global__ __launch_bounds__(256, 1) void grud_rnn(
    const float* __restrict__ Um, const float* __restrict__ Wm, const float* __restrict__ Vm,
    const float* __restrict__ bv, const float* __restrict__ Wdg, const float* __restrict__ bdg,
    const u16* __restrict__ XHAT, const u16* __restrict__ MASKB, const u16* __restrict__ DELTA,
    u16* __restrict__ HDECB, u16* __restrict__ RHB, u16* __restrict__ ZZB,
    u16* __restrict__ GAMB, u16* __restrict__ HALL, u32* __restrict__ flags)
{
  const int tid = threadIdx.x, lane = tid & 63, wid = tid >> 6, bid = blockIdx.x;
  const int cl = bid / 9, role = bid % 9;
  const int RB0 = cl * 2, RB1 = RB0 + 1;
  const int M00 = RB0 * 16, M01 = RB1 * 16;
  const int l16 = lane & 15, krow = lane >> 4;
  const int r4 = lane >> 2, cb = (lane & 3) * 8;
  u32* FB0 = flags + RB0 * 64;
  u32* FB1 = flags + RB1 * 64;

  __shared__ u16 panels[2][80 * 16 * 8];  // 2 A-panels, K=640 (40 KB)
  __shared__ float xb[4][16 * 34];
  __shared__ int s_ab;
  u16* panel0 = panels[0];
  u16* panel1 = panels[1];
  float* xw = xb[wid];
  const f32x4 Z4 = {0.f, 0.f, 0.f, 0.f};
  if (tid == 0) s_ab = 0;
  __syncthreads();

  // merged poll helper: lanes<16 on base16, lanes 16..16+n2-1 on base2
  auto pollw = [&](const u32* base16, u32 tgt16, const u32* base2, u32 tgt2, int n2){
    if (wid == 0) {
      const u32* wp; u32 tgt;
      if (lane < 16)           { wp = base16 + lane; tgt = tgt16; }
      else if (lane < 16 + n2) { wp = base2 + (lane - 16); tgt = tgt2; }
      else                     { wp = base16; tgt = 0u; }
      if (!poll_ge(wp, tgt)) s_ab = 1;
    }
  };

  if (role < 4) {
    // ================= gate WG =================
    const int pw = role * 4 + wid;
    const int cw = role * 128 + wid * 32;
    bfrag BR[20][2], BH[20][2];
    #pragma unroll
    for (int kk = 0; kk < 20; ++kk) {
      const int k0 = kk * 32 + krow * 8;
      #pragma unroll
      for (int t2 = 0; t2 < 2; ++t2) {
        BR[kk][t2] = ldfrag(wsrc(Um, Wm, Vm, 512  + cw + t2 * 16 + l16, k0));
        BH[kk][t2] = ldfrag(wsrc(Um, Wm, Vm, 1024 + cw + t2 * 16 + l16, k0));
      }
    }
    const float br0 = bv[512 + cw + l16],  br1 = bv[512 + cw + 16 + l16];
    const float bh0 = bv[1024 + cw + l16], bh1 = bv[1024 + cw + 16 + l16];

    UQ hd0_, hd1_;

    auto hop1 = [&](u16* pan, int m0x, u32* FBX, UQ& hdx, int t){
      stage_bf16(pan, HDECB + (size_t)m0x * 512, tid, t == 0);
      __syncthreads();
      f32x4 A0 = {br0, br0, br0, br0}, A1 = {br1, br1, br1, br1};
      #pragma unroll
      for (int kk = 0; kk < 20; ++kk) {
        bfrag a = *(const bfrag*)&pan[((kk * 4 + krow) * 16 + l16) * 8];
        A0 = MFMA(a, BR[kk][0], A0); A1 = MFMA(a, BR[kk][1], A1);
      }
      #pragma unroll
      for (int j = 0; j < 4; ++j) {
        xw[(krow * 4 + j) * 34 + l16] = A0[j];
        xw[(krow * 4 + j) * 34 + 16 + l16] = A1[j];
      }
      hdx.h = *(const u16x8*)&pan[(((cw + cb) >> 3) * 16 + r4) * 8];
      UQ rh_;
      #pragma unroll
      for (int q = 0; q < 8; ++q) {
        float rv = sigm(xw[r4 * 34 + cb + q]);
        rh_.h[q] = f2b(rv * b2f(hdx.h[q]));
      }
      u16* rdst = RHB + (size_t)(m0x + r4) * 512 + cw + cb;
      cstore64(rdst, rh_.u[0]); cstore64(rdst + 4, rh_.u[1]);
      asm volatile("s_waitcnt vmcnt(0)" ::: "memory");
      if (lane == 0) cstore32(FBX + 16 + pw, (u32)(t + 1));
    };

    auto hop2 = [&](u16* pan, int m0x, u32* FBX, UQ& hdx, u64 gma, u64 gmb, int t){
      stage_bf16(pan, RHB + (size_t)m0x * 512, tid, false);
      __syncthreads();
      u64 zz0 = cload64(ZZB + (size_t)(m0x + r4) * 512 + cw + cb);
      u64 zz1 = cload64(ZZB + (size_t)(m0x + r4) * 512 + cw + cb + 4);
      f32x4 H0 = {bh0, bh0, bh0, bh0}, H1 = {bh1, bh1, bh1, bh1};
      #pragma unroll
      for (int kk = 0; kk < 20; ++kk) {
        bfrag a = *(const bfrag*)&pan[((kk * 4 + krow) * 16 + l16) * 8];
        H0 = MFMA(a, BH[kk][0], H0); H1 = MFMA(a, BH[kk][1], H1);
      }
      #pragma unroll
      for (int j = 0; j < 4; ++j) {
        xw[(krow * 4 + j) * 34 + l16] = H0[j];
        xw[(krow * 4 + j) * 34 + 16 + l16] = H1[j];
      }
      UQ zz_; zz_.u[0] = zz0; zz_.u[1] = zz1;
      UQ gm_; gm_.u[0] = gma; gm_.u[1] = gmb;
      UQ hw_, hdn_;
      #pragma unroll
      for (int q = 0; q < 8; ++q) {
        float til = tanh_f(xw[r4 * 34 + cb + q]);
        float z = b2f(zz_.h[q]);
        float hn = (1.f - z) * b2f(hdx.h[q]) + z * til;
        hw_.h[q] = f2b(hn);
        hdn_.h[q] = f2b(b2f(gm_.h[q]) * hn);
      }
      if (t + 1 < NS) {
        u16* hdst = HDECB + (size_t)(m0x + r4) * 512 + cw + cb;
        cstore64(hdst, hdn_.u[0]); cstore64(hdst + 4, hdn_.u[1]);
      }
      asm volatile("s_waitcnt vmcnt(0)" ::: "memory");
      if (lane == 0) cstore32(FBX + 0 + pw, (u32)(t + 1));
      u16* hp = HALL + ((size_t)t * NB + m0x + r4) * 512 + cw + cb;
      *(u64*)hp = hw_.u[0]; *(u64*)(hp + 4) = hw_.u[1];
    };

    for (int t = 0; t < NS; ++t) {
      { // stage x_hat/mask for BOTH rbs (static, plain cached loads)
        const int kbx = tid >> 4, row = tid & 15;
        const u16* s0 = (kbx < 8 ? XHAT : MASKB) + ((size_t)t * NB + M00 + row) * 64 + (kbx & 7) * 8;
        *(uint4*)&panel0[((64 + kbx) * 16 + row) * 8] = *(const uint4*)s0;
        const u16* s1 = (kbx < 8 ? XHAT : MASKB) + ((size_t)t * NB + M01 + row) * 64 + (kbx & 7) * 8;
        *(uint4*)&panel1[((64 + kbx) * 16 + row) * 8] = *(const uint4*)s1;
      }
      const u32 gtgt = (u32)((t + 1 < NS) ? (t + 1) : (NS - 1));
      // ---- rb0 hop1 ----
      pollw(FB0 + 0, (u32)t, FB0 + 48, gtgt, 1);
      __syncthreads();
      if (s_ab) break;
      u64 g00 = 0, g01 = 0;
      if (t + 1 < NS) {
        const u16* gp = GAMB + (((size_t)((t + 1) & 1) * 16 + RB0) * 16 + r4) * 512 + cw + cb;
        g00 = cload64(gp); g01 = cload64(gp + 4);
      }
      hop1(panel0, M00, FB0, hd0_, t);
      // ---- rb1 hop1 ----
      pollw(FB1 + 0, (u32)t, FB1 + 48, gtgt, 1);
      __syncthreads();
      if (s_ab) break;
      u64 g10 = 0, g11 = 0;
      if (t + 1 < NS) {
        const u16* gp = GAMB + (((size_t)((t + 1) & 1) * 16 + RB1) * 16 + r4) * 512 + cw + cb;
        g10 = cload64(gp); g11 = cload64(gp + 4);
      }
      hop1(panel1, M01, FB1, hd1_, t);
      // ---- rb0 hop2 ----
      pollw(FB0 + 16, (u32)(t + 1), FB0 + 32, (u32)(t + 1), 16);
      __syncthreads();
      if (s_ab) break;
      hop2(panel0, M00, FB0, hd0_, g00, g01, t);
      // ---- rb1 hop2 ----
      pollw(FB1 + 16, (u32)(t + 1), FB1 + 32, (u32)(t + 1), 16);
      __syncthreads();
      if (s_ab) break;
      hop2(panel1, M01, FB1, hd1_, g10, g11, t);
      __syncthreads();   // protect panels before next-iter staging
    }
  } else if (role < 8) {
    // ================= z WG =================
    const int pw = (role - 4) * 4 + wid;
    const int cw = (role - 4) * 128 + wid * 32;
    bfrag BZ[20][2];
    #pragma unroll
    for (int kk = 0; kk < 20; ++kk) {
      const int k0 = kk * 32 + krow * 8;
      #pragma unroll
      for (int t2 = 0; t2 < 2; ++t2)
        BZ[kk][t2] = ldfrag(wsrc(Um, Wm, Vm, cw + t2 * 16 + l16, k0));
    }
    const float bz0 = bv[cw + l16], bz1 = bv[cw + 16 + l16];

    auto zhop = [&](u16* pan, int m0x, u32* FBX, int t){
      stage_bf16(pan, HDECB + (size_t)m0x * 512, tid, t == 0);
      __syncthreads();
      f32x4 A0 = {bz0, bz0, bz0, bz0}, A1 = {bz1, bz1, bz1, bz1};
      #pragma unroll
      for (int kk = 0; kk < 20; ++kk) {
        bfrag a = *(const bfrag*)&pan[((kk * 4 + krow) * 16 + l16) * 8];
        A0 = MFMA(a, BZ[kk][0], A0); A1 = MFMA(a, BZ[kk][1], A1);
      }
      #pragma unroll
      for (int j = 0; j < 4; ++j) {
        xw[(krow * 4 + j) * 34 + l16] = A0[j];
        xw[(krow * 4 + j) * 34 + 16 + l16] = A1[j];
      }
      UQ zq;
      #pragma unroll
      for (int q = 0; q < 8; ++q) zq.h[q] = f2b(sigm(xw[r4 * 34 + cb + q]));
      u16* zdst = ZZB + (size_t)(m0x + r4) * 512 + cw + cb;
      cstore64(zdst, zq.u[0]); cstore64(zdst + 4, zq.u[1]);
      asm volatile("s_waitcnt vmcnt(0)" ::: "memory");
      if (lane == 0) cstore32(FBX + 32 + pw, (u32)(t + 1));
    };

    for (int t = 0; t < NS; ++t) {
      { const int kbx = tid >> 4, row = tid & 15;
        const u16* s0 = (kbx < 8 ? XHAT : MASKB) + ((size_t)t * NB + M00 + row) * 64 + (kbx & 7) * 8;
        *(uint4*)&panel0[((64 + kbx) * 16 + row) * 8] = *(const uint4*)s0;
        const u16* s1 = (kbx < 8 ? XHAT : MASKB) + ((size_t)t * NB + M01 + row) * 64 + (kbx & 7) * 8;
        *(uint4*)&panel1[((64 + kbx) * 16 + row) * 8] = *(const uint4*)s1; }
      pollw(FB0 + 0, (u32)t, FB0, 0u, 0);
      __syncthreads();
      if (s_ab) break;
      zhop(panel0, M00, FB0, t);
      pollw(FB1 + 0, (u32)t, FB1, 0u, 0);
      __syncthreads();
      if (s_ab) break;
      zhop(panel1, M01, FB1, t);
      __syncthreads();
    }
  } else {
    // ================= gamma producer (both rbs) =================
    bfrag BG[8][2];
    #pragma unroll
    for (int ct = 0; ct < 8; ++ct)
      #pragma unroll
      for (int kx = 0; kx < 2; ++kx)
        BG[ct][kx] = ldfrag(Wdg + (size_t)(wid * 128 + ct * 16 + l16) * 64 + kx * 32 + krow * 8);
    float gb4[4][8];
    #pragma unroll
    for (int grp = 0; grp < 4; ++grp)
      #pragma unroll
      for (int q = 0; q < 8; ++q) gb4[grp][q] = bdg[wid * 128 + grp * 32 + cb + q];

    auto ghop = [&](u16* pan, int rbx, int m0x, u32* FBX, int tt){
      if (wid == 0) {
        const u32* wp = (lane < 16) ? (FBX + lane) : FBX;
        u32 tgt = (lane < 16 && tt >= 3) ? (u32)(tt - 2) : 0u;
        if (!poll_ge(wp, tgt)) s_ab = 1;
      }
      if (tid < 128) {
        const int kb = tid >> 4, row = tid & 15;
        const u16* sp = DELTA + ((size_t)tt * NB + m0x + row) * 64 + kb * 8;
        *(uint4*)&pan[(kb * 16 + row) * 8] = *(const uint4*)sp;
      }
      __syncthreads();
      if (s_ab) return false;
      u16* orow_ = GAMB + (((size_t)(tt & 1) * 16 + rbx) * 16 + r4) * 512 + wid * 128;
      #pragma unroll
      for (int grp = 0; grp < 4; ++grp) {
        f32x4 ac0 = Z4, ac1 = Z4;
        #pragma unroll
        for (int kx = 0; kx < 2; ++kx) {
          bfrag a = *(const bfrag*)&pan[((kx * 4 + krow) * 16 + l16) * 8];
          ac0 = MFMA(a, BG[grp * 2][kx], ac0); ac1 = MFMA(a, BG[grp * 2 + 1][kx], ac1);
        }
        #pragma unroll
        for (int j = 0; j < 4; ++j) { xw[(krow*4+j)*34 + l16] = ac0[j]; xw[(krow*4+j)*34 + 16 + l16] = ac1[j]; }
        UQ ov;
        #pragma unroll
        for (int q = 0; q < 8; ++q)
          ov.h[q] = f2b(__expf(-fmaxf(0.f, xw[r4 * 34 + cb + q] + gb4[grp][q])));
        cstore64(orow_ + grp * 32 + cb, ov.u[0]); cstore64(orow_ + grp * 32 + cb + 4, ov.u[1]);
      }
      asm volatile("s_waitcnt vmcnt(0)" ::: "memory");
      __syncthreads();
      if (tid == 0) cstore32(FBX + 48, (u32)tt);
      return true;
    };

    for (int tt = 1; tt < NS; ++tt) {
      if (!ghop(panel0, RB0, M00, FB0, tt)) break;
      if (!ghop(panel1, RB1, M01, FB1, tt)) break;
    }
  }
}

// ---------------- post kernels ----------------

__global__ void attn_k(const u16* __restrict__ HALL, const float* __restrict__ av,
                       float* __restrict__ ATTN){
  const int b = blockIdx.x, tid = threadIdx.x, lane = tid & 63, wid = tid >> 6;
  __shared__ float avs[512], wgt[256], red[8];
  for (int i = tid; i < 512; i += 256) avs[i] = av[i];
  __syncthreads();
  float val = -3.0e38f;
  if (tid < NS) {
    const u16* hp = HALL + ((size_t)tid * NB + b) * 512;
    float acc = 0.f;
    for (int h = 0; h < 512; h += 8) {
      UQ w; w.q = *(const uint4*)(hp + h);
      #pragma unroll
      for (int j = 0; j < 8; ++j) acc += b2f(w.h[j]) * avs[h + j];
    }
    val = acc * 0.04419417382415922f;   // 1/sqrt(512)
  }
  float m = val;
  #pragma unroll
  for (int off = 32; off; off >>= 1) m = fmaxf(m, __shfl_xor(m, off, 64));
  if (lane == 0) red[wid] = m;
  __syncthreads();
  m = fmaxf(fmaxf(red[0], red[1]), fmaxf(red[2], red[3]));
  float e = (tid < NS) ? __expf(val - m) : 0.f;
  float sum = e;
  #pragma unroll
  for (int off = 32; off; off >>= 1) sum += __shfl_xor(sum, off, 64);
  if (lane == 0) red[4 + wid] = sum;
  __syncthreads();
  const float ssum = red[4] + red[5] + red[6] + red[7];
  wgt[tid] = e / ssum;
  __syncthreads();
  float a0 = 0.f, a1 = 0.f;
  const int h0 = tid * 2;
  for (int s = 0; s < NS; ++s) {
    float w = wgt[s];
    u32 pr = *(const u32*)(HALL + ((size_t)s * NB + b) * 512 + h0);
    a0 += w * b2f((u16)(pr & 0xFFFFu));
    a1 += w * b2f((u16)(pr >> 16));
  }
  ATTN[(size_t)b * 512 + h0] = a0;
  ATTN[(size_t)b * 512 + h0 + 1] = a1;
}

__global__ void out_k(const float* __restrict__ ATTN, const float* __restrict__ Ain,
                      const float* __restrict__ WT, const float* __restrict__ bout,
                      float* __restrict__ OUT){
  const int g = blockIdx.x, tid = threadIdx.x;
  __shared__ float ah[4][520];
  for (int i = tid; i < 4 * 520; i += 256) {
    int bb = i / 520, k = i % 520;
    int b = g * 4 + bb;
    ah[bb][k] = (k < 512) ? ATTN[(size_t)b * 512 + k] : Ain[b * 8 + (k - 512)];
  }
  __syncthreads();
  #pragma unroll
  for (int part = 0; part < 2; ++part) {
    const int ho = part * 256 + tid;
    float a0 = bout[ho], a1 = a0, a2 = a0, a3 = a0;
    for (int k = 0; k < 520; ++k) {
      float w = WT[(size_t)k * 512 + ho];
      a0 += ah[0][k] * w; a1 += ah[1][k] * w; a2 += ah[2][k] * w; a3 += ah[3][k] * w;
    }
    OUT[(size_t)(g * 4 + 0) * 512 + ho] = a0;
    OUT[(size_t)(g * 4 + 1) * 512 + ho] = a1;
    OUT[(size_t)(g * 4 + 2) * 512 + ho] = a2;
    OUT[(size_t)(g * 4 + 3) * 512 + ho] = a3;
  }
}

// ---------------- host ----------------

extern "C" void kernel_launch(void* const* d_in, const int* in_sizes, int n_in,
                              void* d_out, int out_size, void* d_ws, size_t ws_size,
                              hipStream_t stream) {
  (void)in_sizes; (void)n_in; (void)out_size; (void)ws_size;
  const float* x    = (const float*)d_in[0];
  const float* a_in = (const float*)d_in[1];
  const float* tc   = (const float*)d_in[2];
  const float* mask = (const float*)d_in[3];
  const float* wdgx = (const float*)d_in[4];
  const float* bdgx = (const float*)d_in[5];
  const float* Wdgh = (const float*)d_in[6];
  const float* bdgh = (const float*)d_in[7];
  const float* Wm   = (const float*)d_in[8];
  const float* Um   = (const float*)d_in[9];
  const float* Vm   = (const float*)d_in[10];
  const float* bvv  = (const float*)d_in[11];
  const float* attv = (const float*)d_in[12];
  const float* Wout = (const float*)d_in[13];
  const float* bout = (const float*)d_in[14];

  char* ws = (char*)d_ws;
  size_t o = 0;
  auto al = [&](size_t sz) { size_t r = o; o += (sz + 255) & ~(size_t)255; return r; };
  u32*   flags = (u32*)  (ws + al(16 * 64 * 4));
  float* XMEAN = (float*)(ws + al(256));
  float* PX    = (float*)(ws + al((size_t)NS * 64 * 4));
  float* PM    = (float*)(ws + al((size_t)NS * 64 * 4));
  u16*   XHAT  = (u16*)  (ws + al((size_t)NS * NB * 64 * 2));
  u16*   MASKB = (u16*)  (ws + al((size_t)NS * NB * 64 * 2));
  u16*   DELTA = (u16*)  (ws + al((size_t)NS * NB * 64 * 2));
  u16*   HDECB = (u16*)  (ws + al((size_t)NB * NH * 2));
  u16*   RHB   = (u16*)  (ws + al((size_t)NB * NH * 2));
  u16*   ZZB   = (u16*)  (ws + al((size_t)NB * NH * 2));
  u16*   GAMB  = (u16*)  (ws + al((size_t)2 * 16 * 16 * 512 * 2));
  u16*   HALL  = (u16*)  (ws + al((size_t)NS * NB * NH * 2));
  float* ATTN  = (float*)(ws + al((size_t)NB * NH * 4));
  float* WT    = (float*)(ws + al((size_t)520 * 512 * 4));

  hipMemsetAsync(flags, 0, 16 * 64 * 4, stream);

  transpose_k<<<(520 * 512 + 255) / 256, 256, 0, stream>>>(Wout, WT);
  mean1_k<<<NS, 256, 0, stream>>>(x, mask, PX, PM);
  mean2_k<<<1, 64, 0, stream>>>(PX, PM, XMEAN);
  prep_k<<<NB * ND / 256, 256, 0, stream>>>(x, mask, tc, wdgx, bdgx, XMEAN, XHAT, MASKB, DELTA);
  grud_rnn<<<72, 256, 0, stream>>>(Um, Wm, Vm, bvv, Wdgh, bdgh, XHAT, MASKB, DELTA,
                                   HDECB, RHB, ZZB, GAMB, HALL, flags);
  attn_k<<<NB, 256, 0, stream>>>(HALL, attv, ATTN);
  out_k<<<64, 256, 0, stream>>>(ATTN, a_in, WT, bout, (float*)d_out);
}